// Round 8
// baseline (746.952 us; speedup 1.0000x reference)
//
#include <hip/hip_runtime.h>

#define NIN 10517

__device__ __forceinline__ float lrelu02(float x){ return x > 0.f ? x : 0.2f*x; }
__device__ __forceinline__ float fast_tanh(float x){ float e=__expf(2.f*x); return 1.f - 2.f/(e+1.f); }
__device__ __forceinline__ float fast_sig(float x){ return 1.f/(1.f+__expf(-x)); }

// Sum over the 4 K-quarter lanes (lane ^16 then ^32) entirely in the VALU.
__device__ __forceinline__ float quarter_reduce(float a){
  float s;
  asm volatile("v_mov_b32 %0, %1\n\t"
               "v_permlane16_swap_b32 %0, %1\n\t"
               "v_add_f32 %1, %0, %1"
               : "=&v"(s), "+v"(a));
  asm volatile("v_mov_b32 %0, %1\n\t"
               "v_permlane32_swap_b32 %0, %1\n\t"
               "v_add_f32 %1, %0, %1"
               : "=&v"(s), "+v"(a));
  return a;
}

// pin a loaded float4 into registers (forces load completion at the pin,
// prevents sinking/remat of the staged weights)
#define PIN4(v) asm volatile("" : "+v"((v).x), "+v"((v).y), "+v"((v).z), "+v"((v).w))

// light barrier: order LDS writes->reads without draining vmcnt (keeps the
// step-top weight/gi loads and hs stores in flight across phases)
#define LBAR() do { asm volatile("s_waitcnt lgkmcnt(0)" ::: "memory"); \
                    __builtin_amdgcn_s_barrier(); } while (0)

// ---------------- K1a: FC (384->256, relu) + Wh0 (256->128) + s,d per head ----------------
__global__ __launch_bounds__(256) void k_fc_gat(const float* __restrict__ inputs,
    const float* __restrict__ fc_w, const float* __restrict__ fc_b,
    const float* __restrict__ gat_w, const float* __restrict__ a_src, const float* __restrict__ a_dst,
    float* __restrict__ wh0_ws, float* __restrict__ sd_ws)
{
  __shared__ float xin[16][384];
  __shared__ float xfc[16][256];
  __shared__ float wh[16][128];
  const int tid = threadIdx.x;
  const int bt0 = blockIdx.x * 16;
  for (int idx = tid; idx < 16*384; idx += 256) {
    int r = idx / 384, f = idx - r*384;
    xin[r][f] = inputs[(size_t)(bt0+r)*NIN + 10133 + f];
  }
  __syncthreads();
  {
    float acc[16];
    float bj = fc_b[tid];
    #pragma unroll
    for (int r=0;r<16;r++) acc[r] = bj;
    for (int f=0; f<384; f++) {
      float wf = fc_w[f*256 + tid];
      #pragma unroll
      for (int r=0;r<16;r++) acc[r] = fmaf(xin[r][f], wf, acc[r]);
    }
    #pragma unroll
    for (int r=0;r<16;r++) xfc[r][tid] = fmaxf(acc[r], 0.f);
  }
  __syncthreads();
  {
    const int j2 = tid & 127, r0 = (tid >> 7) * 8;
    float acc[8];
    #pragma unroll
    for (int r=0;r<8;r++) acc[r] = 0.f;
    for (int f=0; f<256; f++) {
      float wf = gat_w[f*128 + j2];
      #pragma unroll
      for (int r=0;r<8;r++) acc[r] = fmaf(xfc[r0+r][f], wf, acc[r]);
    }
    #pragma unroll
    for (int r=0;r<8;r++) {
      wh[r0+r][j2] = acc[r];
      wh0_ws[(size_t)(bt0+r0+r)*128 + j2] = acc[r];
    }
  }
  __syncthreads();
  if (tid < 128) {
    const int r = tid >> 3, h = (tid >> 1) & 3, w = tid & 1;
    const float* av = w ? a_dst : a_src;
    float acc = 0.f;
    #pragma unroll
    for (int d=0; d<32; d++) acc = fmaf(wh[r][h*32+d], av[h*32+d], acc);
    sd_ws[(size_t)(bt0+r)*8 + w*4 + h] = acc;
  }
}

// ---------------- K1b: adjacency stats + closed-form alpha + x_gat + gi (fused) ----------------
__global__ __launch_bounds__(256) void k_alpha_gi(const float* __restrict__ inputs,
    const float* __restrict__ wh0_ws, const float* __restrict__ sd_ws,
    const float* __restrict__ gru_wi, const float* __restrict__ gru_bi,
    float* __restrict__ gi_ws)
{
  __shared__ int cnt[100];
  __shared__ int a0f[100];
  __shared__ float alpha[4][100];
  __shared__ float wh0[128];
  __shared__ float sdl[8];
  __shared__ float xg[128];
  const int tid = threadIdx.x;
  const size_t bt = blockIdx.x;
  if (tid < 128) wh0[tid] = wh0_ws[bt*128 + tid];
  if (tid < 8) sdl[tid] = sd_ws[bt*8 + tid];
  const float* adj = inputs + bt*NIN + 132;
  const int wv = tid >> 6, lane = tid & 63;
  for (int i = wv; i < 100; i += 4) {
    float v0 = adj[i*100 + lane];
    int pred0 = (lane != 0) && ((v0 > 0.f) || (lane == i));
    unsigned long long b0 = __ballot(pred0);
    int pred1 = 0;
    if (lane < 36) {
      float v1 = adj[i*100 + 64 + lane];
      pred1 = (v1 > 0.f) || ((64 + lane) == i);
    }
    unsigned long long b1 = __ballot(pred1);
    if (lane == 0) {
      cnt[i] = __popcll(b0) + __popcll(b1);
      a0f[i] = (v0 > 0.f) ? 1 : 0;
    }
  }
  __syncthreads();
  for (int idx = tid; idx < 400; idx += 256) {
    int h = idx / 100, i = idx - h*100;
    float s = sdl[h], d = sdl[4+h];
    float a;
    if (i == 0) {
      float ea = __expf(lrelu02(s + d));
      float eb = __expf(lrelu02(s));
      a = ea / (ea + (float)cnt[0] * eb);
    } else if (a0f[i]) {
      float ed = __expf(lrelu02(d));
      a = ed / (ed + (float)cnt[i]);
    } else {
      a = 0.f;
    }
    alpha[h][i] = a;
  }
  __syncthreads();
  if (tid < 128) {
    const int h = tid >> 5;
    const float w = wh0[tid];
    float sum = 0.f;
    for (int i=0;i<100;i++) {
      float t = alpha[h][i] * w;
      sum += (t > 0.f) ? t : (__expf(t) - 1.f);  // elu
    }
    xg[tid] = sum * 0.01f;  // mean over N=100
  }
  __syncthreads();
  for (int jj = tid; jj < 384; jj += 256) {
    float acc = gru_bi[jj];
    for (int f=0; f<128; f++) acc = fmaf(xg[f], gru_wi[f*384 + jj], acc);
    gi_ws[bt*384 + jj] = acc;
  }
}

// ---------------- K1c: weight transposes for contiguous per-lane slices ----------------
// w1T[j][k] = ode_w1[k][j]; w2T likewise; ghT[m][k] = gru_wh[k][m] (m in 0..384)
__global__ void k_prep(const float* __restrict__ w1, const float* __restrict__ w2,
                       const float* __restrict__ wh,
                       float* __restrict__ w1T, float* __restrict__ w2T, float* __restrict__ ghT)
{
  int idx = blockIdx.x * 256 + threadIdx.x;
  if (idx < 128*128) {
    int jj = idx >> 7, k = idx & 127;
    w1T[idx] = w1[k*128 + jj];
    w2T[idx] = w2[k*128 + jj];
  }
  if (idx < 384*128) {
    int m = idx >> 7, k = idx & 127;
    ghT[idx] = wh[k*384 + m];
  }
}

// ---------------- K2: RK4-ODE + GRU scan ----------------
// 512 threads (8 waves, 2/SIMD), one block per batch element.
// j = wave*16 + (lane&15), K-quarter p4 = (lane>>4)&3.
// This round: (1) all weights staged into registers at STEP TOP via float4
// loads from pre-transposed copies, pinned so they complete once per step
// (~300cy) instead of refetching inside every phase; (2) light barriers
// (lgkmcnt-only) so global loads/stores float across phases; (3) hs written
// directly to global (fire-and-forget).
__global__ __launch_bounds__(512, 2) void k_rnn(const float* __restrict__ inputs,
    const float* __restrict__ h0,
    const float* __restrict__ w1T, const float* __restrict__ ode_b1,
    const float* __restrict__ w2T, const float* __restrict__ ode_b2,
    const float* __restrict__ ghT, const float* __restrict__ gru_bh,
    const float* __restrict__ gi_ws, float* __restrict__ hs_ws, float* __restrict__ hT_out)
{
  __shared__ __align__(16) float Abuf[144];
  __shared__ __align__(16) float Bbuf[144];
  __shared__ __align__(16) float Cbuf[144];
  __shared__ float dtbuf[64];
  const int tid = threadIdx.x;
  const int b = blockIdx.x;
  const int j  = ((tid >> 6) << 4) | (tid & 15);   // output column
  const int p4 = (tid >> 4) & 3;                    // K-quarter
  const int pj = ((j >> 5) * 36) + (j & 31);        // padded LDS index

  const float4* p1 = reinterpret_cast<const float4*>(w1T + j*128 + p4*32);
  const float4* p2 = reinterpret_cast<const float4*>(w2T + j*128 + p4*32);
  const float4* pa = reinterpret_cast<const float4*>(ghT + (size_t)j*128 + p4*32);
  const float4* pb = reinterpret_cast<const float4*>(ghT + (size_t)(j+128)*128 + p4*32);
  const float4* pc = reinterpret_cast<const float4*>(ghT + (size_t)(j+256)*128 + p4*32);

  const float b1 = ode_b1[j], b2 = ode_b2[j];
  const float bh0 = gru_bh[j], bh1 = gru_bh[j+128], bh2 = gru_bh[j+256];
  float h = h0[b*128 + j];
  if (tid < 64) dtbuf[tid] = inputs[((size_t)b*64 + tid)*NIN + 10132];
  if (p4 == 0) Cbuf[pj] = h;
  const float* gib = gi_ws + (size_t)b*64*384 + j;
  __syncthreads();   // full barrier once at init

  auto mv = [&](const float* __restrict__ src, const float4 (&Wv)[8], float bias)->float {
    const float4* s4 = reinterpret_cast<const float4*>(src + p4*36);
    float a0=0.f,a1=0.f,a2=0.f,a3=0.f;
    #pragma unroll
    for (int q=0;q<8;q++){
      float4 hv = s4[q]; float4 wv = Wv[q];
      a0 = fmaf(hv.x, wv.x, a0);
      a1 = fmaf(hv.y, wv.y, a1);
      a2 = fmaf(hv.z, wv.z, a2);
      a3 = fmaf(hv.w, wv.w, a3);
    }
    float a = quarter_reduce((a0+a1)+(a2+a3));
    return fast_tanh(a + bias);
  };

  for (int t=0; t<64; t++) {
    // ---- step-top staging: all weights + this step's gi, pinned ----
    float4 W1v[8], W2v[8], GAv[8], GBv[8], GCv[8];
    #pragma unroll
    for (int q=0;q<8;q++){ W1v[q]=p1[q]; W2v[q]=p2[q]; GAv[q]=pa[q]; GBv[q]=pb[q]; GCv[q]=pc[q]; }
    float gir = gib[(size_t)t*384], giz = gib[(size_t)t*384+128], gin = gib[(size_t)t*384+256];
    #pragma unroll
    for (int q=0;q<8;q++){ PIN4(W1v[q]); PIN4(W2v[q]); PIN4(GAv[q]); PIN4(GBv[q]); PIN4(GCv[q]); }
    asm volatile("" : "+v"(gir), "+v"(giz), "+v"(gin));

    const float dt = dtbuf[t];
    float u, k1, k2, k3, k4;
    u  = mv(Cbuf, W1v, b1); if (p4==0) Abuf[pj] = u;                      LBAR();
    k1 = mv(Abuf, W2v, b2); if (p4==0) Bbuf[pj] = fmaf(0.5f*dt, k1, h);   LBAR();
    u  = mv(Bbuf, W1v, b1); if (p4==0) Abuf[pj] = u;                      LBAR();
    k2 = mv(Abuf, W2v, b2); if (p4==0) Bbuf[pj] = fmaf(0.5f*dt, k2, h);   LBAR();
    u  = mv(Bbuf, W1v, b1); if (p4==0) Abuf[pj] = u;                      LBAR();
    k3 = mv(Abuf, W2v, b2); if (p4==0) Bbuf[pj] = fmaf(dt, k3, h);        LBAR();
    u  = mv(Bbuf, W1v, b1); if (p4==0) Abuf[pj] = u;                      LBAR();
    k4 = mv(Abuf, W2v, b2);
    const float h_ode = fmaf(dt*(1.f/6.f), (k1 + 2.f*k2) + (2.f*k3 + k4), h);
    if (p4==0) Bbuf[pj] = h_ode;                                          LBAR();

    // gh = h_ode @ gru_wh (register-staged weights, quarter-K per lane)
    {
      const float4* h4 = reinterpret_cast<const float4*>(Bbuf + p4*36);
      float g0=0.f, g1=0.f, g2=0.f;
      #pragma unroll
      for (int q=0;q<8;q++){
        float4 hv = h4[q];
        float4 av = GAv[q], bv = GBv[q], cv = GCv[q];
        g0 = fmaf(hv.x, av.x, g0); g0 = fmaf(hv.y, av.y, g0);
        g0 = fmaf(hv.z, av.z, g0); g0 = fmaf(hv.w, av.w, g0);
        g1 = fmaf(hv.x, bv.x, g1); g1 = fmaf(hv.y, bv.y, g1);
        g1 = fmaf(hv.z, bv.z, g1); g1 = fmaf(hv.w, bv.w, g1);
        g2 = fmaf(hv.x, cv.x, g2); g2 = fmaf(hv.y, cv.y, g2);
        g2 = fmaf(hv.z, cv.z, g2); g2 = fmaf(hv.w, cv.w, g2);
      }
      g0 = quarter_reduce(g0);
      g1 = quarter_reduce(g1);
      g2 = quarter_reduce(g2);

      const float r = fast_sig(gir + g0 + bh0);
      const float z = fast_sig(giz + g1 + bh1);
      const float n = fast_tanh(gin + r*(g2 + bh2));
      h = (1.f - z)*n + z*h_ode;
    }
    if (p4==0) {
      Cbuf[pj] = h;
      hs_ws[((size_t)b*64 + t)*128 + j] = h;   // fire-and-forget
    }
    LBAR();
  }
  if (p4==0) hT_out[b*128 + j] = h;
}

// ---------------- K3: logits + mask + value ----------------
__global__ __launch_bounds__(256) void k_head(const float* __restrict__ hs_ws,
    const float* __restrict__ act_w, const float* __restrict__ act_b,
    const float* __restrict__ val_w, const float* __restrict__ val_b,
    const float* __restrict__ inputs, float* __restrict__ out_logits, float* __restrict__ out_val)
{
  __shared__ float xr[16][128];
  const int tid = threadIdx.x;
  const int bt0 = blockIdx.x * 16;
  for (int idx = tid; idx < 16*128; idx += 256) {
    int r = idx >> 7, f = idx & 127;
    xr[r][f] = hs_ws[(size_t)(bt0+r)*128 + f];
  }
  __syncthreads();
  if (tid < 132) {
    float acc[16];
    float bj = act_b[tid];
    #pragma unroll
    for (int r=0;r<16;r++) acc[r] = bj;
    for (int f=0; f<128; f++) {
      float wf = act_w[f*132 + tid];
      #pragma unroll
      for (int r=0;r<16;r++) acc[r] = fmaf(xr[r][f], wf, acc[r]);
    }
    #pragma unroll
    for (int r=0;r<16;r++) {
      float mval = inputs[(size_t)(bt0+r)*NIN + tid];
      out_logits[(size_t)(bt0+r)*132 + tid] = (mval == 0.f) ? -1e10f : acc[r];
    }
  } else if (tid >= 136 && tid < 152) {
    int r = tid - 136;
    float acc = val_b[0];
    for (int f=0; f<128; f++) acc = fmaf(xr[r][f], val_w[f], acc);
    out_val[bt0 + r] = acc;
  }
}

extern "C" void kernel_launch(void* const* d_in, const int* in_sizes, int n_in,
                              void* d_out, int out_size, void* d_ws, size_t ws_size,
                              hipStream_t stream) {
  (void)in_sizes; (void)n_in; (void)out_size; (void)ws_size;
  const float* inputs = (const float*)d_in[0];
  const float* h0     = (const float*)d_in[1];
  const float* fc_w   = (const float*)d_in[2];
  const float* fc_b   = (const float*)d_in[3];
  const float* gat_w  = (const float*)d_in[4];
  const float* a_src  = (const float*)d_in[5];
  const float* a_dst  = (const float*)d_in[6];
  const float* ode_w1 = (const float*)d_in[7];
  const float* ode_b1 = (const float*)d_in[8];
  const float* ode_w2 = (const float*)d_in[9];
  const float* ode_b2 = (const float*)d_in[10];
  const float* gru_wi = (const float*)d_in[11];
  const float* gru_wh = (const float*)d_in[12];
  const float* gru_bi = (const float*)d_in[13];
  const float* gru_bh = (const float*)d_in[14];
  const float* act_w  = (const float*)d_in[15];
  const float* act_b  = (const float*)d_in[16];
  const float* val_w  = (const float*)d_in[17];
  const float* val_b  = (const float*)d_in[18];

  float* ws   = (float*)d_ws;
  float* wh0  = ws;               // 2048*128 = 262144
  float* sd   = ws + 262144;      // 2048*8   = 16384
  float* gi   = ws + 278528;      // 2048*384 = 786432
  float* hs   = ws + 1064960;     // 2048*128 = 262144
  float* w1T  = ws + 1327104;     // 128*128  = 16384
  float* w2T  = ws + 1343488;     // 128*128  = 16384
  float* ghT  = ws + 1359872;     // 384*128  = 49152

  float* out        = (float*)d_out;
  float* out_logits = out;            // 2048*132
  float* out_hT     = out + 270336;   // 32*128
  float* out_val    = out + 274432;   // 2048

  k_fc_gat  <<<dim3(128),  dim3(256), 0, stream>>>(inputs, fc_w, fc_b, gat_w, a_src, a_dst, wh0, sd);
  k_prep    <<<dim3(192),  dim3(256), 0, stream>>>(ode_w1, ode_w2, gru_wh, w1T, w2T, ghT);
  k_alpha_gi<<<dim3(2048), dim3(256), 0, stream>>>(inputs, wh0, sd, gru_wi, gru_bi, gi);
  k_rnn     <<<dim3(32),   dim3(512), 0, stream>>>(inputs, h0, w1T, ode_b1, w2T, ode_b2,
                                                   ghT, gru_bh, gi, hs, out_hT);
  k_head    <<<dim3(128),  dim3(256), 0, stream>>>(hs, act_w, act_b, val_w, val_b, inputs,
                                                   out_logits, out_val);
}

// Round 9
// 315.659 us; speedup vs baseline: 2.3663x; 2.3663x over previous
//
#include <hip/hip_runtime.h>

#define NIN 10517

__device__ __forceinline__ float lrelu02(float x){ return x > 0.f ? x : 0.2f*x; }
__device__ __forceinline__ float fast_tanh(float x){ float e=__expf(2.f*x); return 1.f - 2.f/(e+1.f); }
__device__ __forceinline__ float fast_sig(float x){ return 1.f/(1.f+__expf(-x)); }

// Sum over the 4 K-quarter lanes (lane ^16 then ^32) entirely in the VALU.
__device__ __forceinline__ float quarter_reduce(float a){
  float s;
  asm volatile("v_mov_b32 %0, %1\n\t"
               "v_permlane16_swap_b32 %0, %1\n\t"
               "v_add_f32 %1, %0, %1"
               : "=&v"(s), "+v"(a));
  asm volatile("v_mov_b32 %0, %1\n\t"
               "v_permlane32_swap_b32 %0, %1\n\t"
               "v_add_f32 %1, %0, %1"
               : "=&v"(s), "+v"(a));
  return a;
}

// pin a loaded float4 into registers (forces load completion + keeps value live)
#define PIN4(v) asm volatile("" : "+v"((v).x), "+v"((v).y), "+v"((v).z), "+v"((v).w))

// light barrier: order LDS writes->reads without draining vmcnt (gi loads and
// hs stores float across phases)
#define LBAR() do { asm volatile("s_waitcnt lgkmcnt(0)" ::: "memory"); \
                    __builtin_amdgcn_s_barrier(); } while (0)

// ---------------- K1a: FC (384->256, relu) + Wh0 (256->128) + s,d per head ----------------
__global__ __launch_bounds__(256) void k_fc_gat(const float* __restrict__ inputs,
    const float* __restrict__ fc_w, const float* __restrict__ fc_b,
    const float* __restrict__ gat_w, const float* __restrict__ a_src, const float* __restrict__ a_dst,
    float* __restrict__ wh0_ws, float* __restrict__ sd_ws)
{
  __shared__ float xin[16][384];
  __shared__ float xfc[16][256];
  __shared__ float wh[16][128];
  const int tid = threadIdx.x;
  const int bt0 = blockIdx.x * 16;
  for (int idx = tid; idx < 16*384; idx += 256) {
    int r = idx / 384, f = idx - r*384;
    xin[r][f] = inputs[(size_t)(bt0+r)*NIN + 10133 + f];
  }
  __syncthreads();
  {
    float acc[16];
    float bj = fc_b[tid];
    #pragma unroll
    for (int r=0;r<16;r++) acc[r] = bj;
    for (int f=0; f<384; f++) {
      float wf = fc_w[f*256 + tid];
      #pragma unroll
      for (int r=0;r<16;r++) acc[r] = fmaf(xin[r][f], wf, acc[r]);
    }
    #pragma unroll
    for (int r=0;r<16;r++) xfc[r][tid] = fmaxf(acc[r], 0.f);
  }
  __syncthreads();
  {
    const int j2 = tid & 127, r0 = (tid >> 7) * 8;
    float acc[8];
    #pragma unroll
    for (int r=0;r<8;r++) acc[r] = 0.f;
    for (int f=0; f<256; f++) {
      float wf = gat_w[f*128 + j2];
      #pragma unroll
      for (int r=0;r<8;r++) acc[r] = fmaf(xfc[r0+r][f], wf, acc[r]);
    }
    #pragma unroll
    for (int r=0;r<8;r++) {
      wh[r0+r][j2] = acc[r];
      wh0_ws[(size_t)(bt0+r0+r)*128 + j2] = acc[r];
    }
  }
  __syncthreads();
  if (tid < 128) {
    const int r = tid >> 3, h = (tid >> 1) & 3, w = tid & 1;
    const float* av = w ? a_dst : a_src;
    float acc = 0.f;
    #pragma unroll
    for (int d=0; d<32; d++) acc = fmaf(wh[r][h*32+d], av[h*32+d], acc);
    sd_ws[(size_t)(bt0+r)*8 + w*4 + h] = acc;
  }
}

// ---------------- K1b: adjacency stats + closed-form alpha + x_gat + gi (fused) ----------------
__global__ __launch_bounds__(256) void k_alpha_gi(const float* __restrict__ inputs,
    const float* __restrict__ wh0_ws, const float* __restrict__ sd_ws,
    const float* __restrict__ gru_wi, const float* __restrict__ gru_bi,
    float* __restrict__ gi_ws)
{
  __shared__ int cnt[100];
  __shared__ int a0f[100];
  __shared__ float alpha[4][100];
  __shared__ float wh0[128];
  __shared__ float sdl[8];
  __shared__ float xg[128];
  const int tid = threadIdx.x;
  const size_t bt = blockIdx.x;
  if (tid < 128) wh0[tid] = wh0_ws[bt*128 + tid];
  if (tid < 8) sdl[tid] = sd_ws[bt*8 + tid];
  const float* adj = inputs + bt*NIN + 132;
  const int wv = tid >> 6, lane = tid & 63;
  for (int i = wv; i < 100; i += 4) {
    float v0 = adj[i*100 + lane];
    int pred0 = (lane != 0) && ((v0 > 0.f) || (lane == i));
    unsigned long long b0 = __ballot(pred0);
    int pred1 = 0;
    if (lane < 36) {
      float v1 = adj[i*100 + 64 + lane];
      pred1 = (v1 > 0.f) || ((64 + lane) == i);
    }
    unsigned long long b1 = __ballot(pred1);
    if (lane == 0) {
      cnt[i] = __popcll(b0) + __popcll(b1);
      a0f[i] = (v0 > 0.f) ? 1 : 0;
    }
  }
  __syncthreads();
  for (int idx = tid; idx < 400; idx += 256) {
    int h = idx / 100, i = idx - h*100;
    float s = sdl[h], d = sdl[4+h];
    float a;
    if (i == 0) {
      float ea = __expf(lrelu02(s + d));
      float eb = __expf(lrelu02(s));
      a = ea / (ea + (float)cnt[0] * eb);
    } else if (a0f[i]) {
      float ed = __expf(lrelu02(d));
      a = ed / (ed + (float)cnt[i]);
    } else {
      a = 0.f;
    }
    alpha[h][i] = a;
  }
  __syncthreads();
  if (tid < 128) {
    const int h = tid >> 5;
    const float w = wh0[tid];
    float sum = 0.f;
    for (int i=0;i<100;i++) {
      float t = alpha[h][i] * w;
      sum += (t > 0.f) ? t : (__expf(t) - 1.f);  // elu
    }
    xg[tid] = sum * 0.01f;  // mean over N=100
  }
  __syncthreads();
  for (int jj = tid; jj < 384; jj += 256) {
    float acc = gru_bi[jj];
    for (int f=0; f<128; f++) acc = fmaf(xg[f], gru_wi[f*384 + jj], acc);
    gi_ws[bt*384 + jj] = acc;
  }
}

// ---------------- K1c: weight transposes for contiguous per-lane slices ----------------
__global__ void k_prep(const float* __restrict__ w1, const float* __restrict__ w2,
                       const float* __restrict__ wh,
                       float* __restrict__ w1T, float* __restrict__ w2T, float* __restrict__ ghT)
{
  int idx = blockIdx.x * 256 + threadIdx.x;
  if (idx < 128*128) {
    int jj = idx >> 7, k = idx & 127;
    w1T[idx] = w1[k*128 + jj];
    w2T[idx] = w2[k*128 + jj];
  }
  if (idx < 384*128) {
    int m = idx >> 7, k = idx & 127;
    ghT[idx] = wh[k*384 + m];
  }
}

// ---------------- K2: RK4-ODE + GRU scan ----------------
// 512 threads (8 waves), one block per batch element.
// amdgpu_waves_per_eu(2,2): pins the codegen occupancy target at 2 waves/EU
// so the allocator may use the full 256-VGPR tier -> the 160 staged weight
// floats stay register-resident (r4/r5/r8 failures: heuristic targeted
// 4 waves/EU=128 VGPR and remat'd or scratch-spilled the weights).
// Weights staged ONCE before the loop, pinned. Light lgkm-only barriers.
__global__ __launch_bounds__(512)
__attribute__((amdgpu_waves_per_eu(2, 2)))
void k_rnn(const float* __restrict__ inputs,
    const float* __restrict__ h0,
    const float* __restrict__ w1T, const float* __restrict__ ode_b1,
    const float* __restrict__ w2T, const float* __restrict__ ode_b2,
    const float* __restrict__ ghT, const float* __restrict__ gru_bh,
    const float* __restrict__ gi_ws, float* __restrict__ hs_ws, float* __restrict__ hT_out)
{
  __shared__ __align__(16) float Abuf[144];
  __shared__ __align__(16) float Bbuf[144];
  __shared__ __align__(16) float Cbuf[144];
  __shared__ float dtbuf[64];
  const int tid = threadIdx.x;
  const int b = blockIdx.x;
  const int j  = ((tid >> 6) << 4) | (tid & 15);   // output column
  const int p4 = (tid >> 4) & 3;                    // K-quarter
  const int pj = ((j >> 5) * 36) + (j & 31);        // padded LDS index

  // ---- one-time register staging of ALL weights (160 floats/thread) ----
  float4 W1v[8], W2v[8], GAv[8], GBv[8], GCv[8];
  {
    const float4* p1 = reinterpret_cast<const float4*>(w1T + j*128 + p4*32);
    const float4* p2 = reinterpret_cast<const float4*>(w2T + j*128 + p4*32);
    const float4* pa = reinterpret_cast<const float4*>(ghT + (size_t)j*128 + p4*32);
    const float4* pb = reinterpret_cast<const float4*>(ghT + (size_t)(j+128)*128 + p4*32);
    const float4* pc = reinterpret_cast<const float4*>(ghT + (size_t)(j+256)*128 + p4*32);
    #pragma unroll
    for (int q=0;q<8;q++){ W1v[q]=p1[q]; W2v[q]=p2[q]; GAv[q]=pa[q]; GBv[q]=pb[q]; GCv[q]=pc[q]; }
    #pragma unroll
    for (int q=0;q<8;q++){ PIN4(W1v[q]); PIN4(W2v[q]); PIN4(GAv[q]); PIN4(GBv[q]); PIN4(GCv[q]); }
  }

  const float b1 = ode_b1[j], b2 = ode_b2[j];
  const float bh0 = gru_bh[j], bh1 = gru_bh[j+128], bh2 = gru_bh[j+256];
  float h = h0[b*128 + j];
  if (tid < 64) dtbuf[tid] = inputs[((size_t)b*64 + tid)*NIN + 10132];
  if (p4 == 0) Cbuf[pj] = h;
  const float* gib = gi_ws + (size_t)b*64*384 + j;
  __syncthreads();   // full barrier once at init

  auto mv = [&](const float* __restrict__ src, const float4 (&Wv)[8], float bias)->float {
    const float4* s4 = reinterpret_cast<const float4*>(src + p4*36);
    float a0=0.f,a1=0.f,a2=0.f,a3=0.f;
    #pragma unroll
    for (int q=0;q<8;q++){
      float4 hv = s4[q]; float4 wv = Wv[q];
      a0 = fmaf(hv.x, wv.x, a0);
      a1 = fmaf(hv.y, wv.y, a1);
      a2 = fmaf(hv.z, wv.z, a2);
      a3 = fmaf(hv.w, wv.w, a3);
    }
    float a = quarter_reduce((a0+a1)+(a2+a3));
    return fast_tanh(a + bias);
  };

  for (int t=0; t<64; t++) {
    // this step's gi (L2-resident; loads float across lgkm-only barriers)
    float gir = gib[(size_t)t*384], giz = gib[(size_t)t*384+128], gin = gib[(size_t)t*384+256];

    const float dt = dtbuf[t];
    float u, k1, k2, k3, k4;
    u  = mv(Cbuf, W1v, b1); if (p4==0) Abuf[pj] = u;                      LBAR();
    k1 = mv(Abuf, W2v, b2); if (p4==0) Bbuf[pj] = fmaf(0.5f*dt, k1, h);   LBAR();
    u  = mv(Bbuf, W1v, b1); if (p4==0) Abuf[pj] = u;                      LBAR();
    k2 = mv(Abuf, W2v, b2); if (p4==0) Bbuf[pj] = fmaf(0.5f*dt, k2, h);   LBAR();
    u  = mv(Bbuf, W1v, b1); if (p4==0) Abuf[pj] = u;                      LBAR();
    k3 = mv(Abuf, W2v, b2); if (p4==0) Bbuf[pj] = fmaf(dt, k3, h);        LBAR();
    u  = mv(Bbuf, W1v, b1); if (p4==0) Abuf[pj] = u;                      LBAR();
    k4 = mv(Abuf, W2v, b2);
    const float h_ode = fmaf(dt*(1.f/6.f), (k1 + 2.f*k2) + (2.f*k3 + k4), h);
    if (p4==0) Bbuf[pj] = h_ode;                                          LBAR();

    // gh = h_ode @ gru_wh (register-resident weights, quarter-K per lane)
    {
      const float4* h4 = reinterpret_cast<const float4*>(Bbuf + p4*36);
      float g0=0.f, g1=0.f, g2=0.f;
      #pragma unroll
      for (int q=0;q<8;q++){
        float4 hv = h4[q];
        float4 av = GAv[q], bv = GBv[q], cv = GCv[q];
        g0 = fmaf(hv.x, av.x, g0); g0 = fmaf(hv.y, av.y, g0);
        g0 = fmaf(hv.z, av.z, g0); g0 = fmaf(hv.w, av.w, g0);
        g1 = fmaf(hv.x, bv.x, g1); g1 = fmaf(hv.y, bv.y, g1);
        g1 = fmaf(hv.z, bv.z, g1); g1 = fmaf(hv.w, bv.w, g1);
        g2 = fmaf(hv.x, cv.x, g2); g2 = fmaf(hv.y, cv.y, g2);
        g2 = fmaf(hv.z, cv.z, g2); g2 = fmaf(hv.w, cv.w, g2);
      }
      g0 = quarter_reduce(g0);
      g1 = quarter_reduce(g1);
      g2 = quarter_reduce(g2);

      const float r = fast_sig(gir + g0 + bh0);
      const float z = fast_sig(giz + g1 + bh1);
      const float n = fast_tanh(gin + r*(g2 + bh2));
      h = (1.f - z)*n + z*h_ode;
    }
    if (p4==0) {
      Cbuf[pj] = h;
      hs_ws[((size_t)b*64 + t)*128 + j] = h;   // fire-and-forget
    }
    LBAR();
  }
  if (p4==0) hT_out[b*128 + j] = h;
}

// ---------------- K3: logits + mask + value ----------------
__global__ __launch_bounds__(256) void k_head(const float* __restrict__ hs_ws,
    const float* __restrict__ act_w, const float* __restrict__ act_b,
    const float* __restrict__ val_w, const float* __restrict__ val_b,
    const float* __restrict__ inputs, float* __restrict__ out_logits, float* __restrict__ out_val)
{
  __shared__ float xr[16][128];
  const int tid = threadIdx.x;
  const int bt0 = blockIdx.x * 16;
  for (int idx = tid; idx < 16*128; idx += 256) {
    int r = idx >> 7, f = idx & 127;
    xr[r][f] = hs_ws[(size_t)(bt0+r)*128 + f];
  }
  __syncthreads();
  if (tid < 132) {
    float acc[16];
    float bj = act_b[tid];
    #pragma unroll
    for (int r=0;r<16;r++) acc[r] = bj;
    for (int f=0; f<128; f++) {
      float wf = act_w[f*132 + tid];
      #pragma unroll
      for (int r=0;r<16;r++) acc[r] = fmaf(xr[r][f], wf, acc[r]);
    }
    #pragma unroll
    for (int r=0;r<16;r++) {
      float mval = inputs[(size_t)(bt0+r)*NIN + tid];
      out_logits[(size_t)(bt0+r)*132 + tid] = (mval == 0.f) ? -1e10f : acc[r];
    }
  } else if (tid >= 136 && tid < 152) {
    int r = tid - 136;
    float acc = val_b[0];
    for (int f=0; f<128; f++) acc = fmaf(xr[r][f], val_w[f], acc);
    out_val[bt0 + r] = acc;
  }
}

extern "C" void kernel_launch(void* const* d_in, const int* in_sizes, int n_in,
                              void* d_out, int out_size, void* d_ws, size_t ws_size,
                              hipStream_t stream) {
  (void)in_sizes; (void)n_in; (void)out_size; (void)ws_size;
  const float* inputs = (const float*)d_in[0];
  const float* h0     = (const float*)d_in[1];
  const float* fc_w   = (const float*)d_in[2];
  const float* fc_b   = (const float*)d_in[3];
  const float* gat_w  = (const float*)d_in[4];
  const float* a_src  = (const float*)d_in[5];
  const float* a_dst  = (const float*)d_in[6];
  const float* ode_w1 = (const float*)d_in[7];
  const float* ode_b1 = (const float*)d_in[8];
  const float* ode_w2 = (const float*)d_in[9];
  const float* ode_b2 = (const float*)d_in[10];
  const float* gru_wi = (const float*)d_in[11];
  const float* gru_wh = (const float*)d_in[12];
  const float* gru_bi = (const float*)d_in[13];
  const float* gru_bh = (const float*)d_in[14];
  const float* act_w  = (const float*)d_in[15];
  const float* act_b  = (const float*)d_in[16];
  const float* val_w  = (const float*)d_in[17];
  const float* val_b  = (const float*)d_in[18];

  float* ws   = (float*)d_ws;
  float* wh0  = ws;               // 2048*128 = 262144
  float* sd   = ws + 262144;      // 2048*8   = 16384
  float* gi   = ws + 278528;      // 2048*384 = 786432
  float* hs   = ws + 1064960;     // 2048*128 = 262144
  float* w1T  = ws + 1327104;     // 128*128  = 16384
  float* w2T  = ws + 1343488;     // 128*128  = 16384
  float* ghT  = ws + 1359872;     // 384*128  = 49152

  float* out        = (float*)d_out;
  float* out_logits = out;            // 2048*132
  float* out_hT     = out + 270336;   // 32*128
  float* out_val    = out + 274432;   // 2048

  k_fc_gat  <<<dim3(128),  dim3(256), 0, stream>>>(inputs, fc_w, fc_b, gat_w, a_src, a_dst, wh0, sd);
  k_prep    <<<dim3(192),  dim3(256), 0, stream>>>(ode_w1, ode_w2, gru_wh, w1T, w2T, ghT);
  k_alpha_gi<<<dim3(2048), dim3(256), 0, stream>>>(inputs, wh0, sd, gru_wi, gru_bi, gi);
  k_rnn     <<<dim3(32),   dim3(512), 0, stream>>>(inputs, h0, w1T, ode_b1, w2T, ode_b2,
                                                   ghT, gru_bh, gi, hs, out_hT);
  k_head    <<<dim3(128),  dim3(256), 0, stream>>>(hs, act_w, act_b, val_w, val_b, inputs,
                                                   out_logits, out_val);
}